// Round 5
// baseline (1237.611 us; speedup 1.0000x reference)
//
#include <hip/hip_runtime.h>
#include <hip/hip_bf16.h>
#include <math.h>

// B=32, S=2048, D=128 causal attention.
// Inputs q,k,v FP32 (mask input ignored; causal by index).
// Outputs (a[B,S,S], out[B,S,D]) concatenated in d_out as FP32.
//
// Round-3 (resubmitted after infra failure in Round 4):
//  - Pass 1 LDS-free + barrier-free: S^T = mfma(A=K_frag_global, B=Q),
//    per-lane (m,l) with 2-shuffle quad reduction. Pass-1 waves fully async.
//  - vt XOR column-group swizzle: staging writes 16-way -> 4-way conflicts,
//    b128 PV reads stay conflict-free.
//  - Keep: balanced pairing, lgkm-only barriers, pass-2 reg prefetch,
//    setprio around MFMA, XCD-clustered grid decode.

typedef __attribute__((ext_vector_type(8))) short bf16x8;   // 8 bf16 = 4 VGPRs
typedef __attribute__((ext_vector_type(4))) short bf16x4;   // 4 bf16 = 2 VGPRs
typedef __attribute__((ext_vector_type(4))) float f32x4;

#define MFMA(a, b, c) __builtin_amdgcn_mfma_f32_16x16x32_bf16((a), (b), (c), 0, 0, 0)

constexpr int   Sdim  = 2048;
constexpr int   Ddim  = 128;
constexpr int   BATCH = 32;
constexpr int   NT    = Sdim / 64;               // 32 q-tiles
constexpr float INV_SCALE = 0.08838834764831845f;  // 1/sqrt(128)
constexpr float NEG_BIG   = -1e30f;
constexpr int   KPAD = 8;
constexpr int   PADV = 8;
constexpr int   PADP = 8;

// Barrier that waits only on LDS ops (lgkmcnt), not outstanding global
// stores/loads. All inter-wave communication is through LDS.
__device__ __forceinline__ void bar_lds() {
    asm volatile("s_waitcnt lgkmcnt(0)\n\ts_barrier" ::: "memory");
}

__device__ __forceinline__ bf16x8 pack8(const float* p) {
    float4 a = *(const float4*)p;
    float4 b = *(const float4*)(p + 4);
    union { __hip_bfloat16 h[8]; bf16x8 v; } u;
    u.h[0] = __float2bfloat16(a.x); u.h[1] = __float2bfloat16(a.y);
    u.h[2] = __float2bfloat16(a.z); u.h[3] = __float2bfloat16(a.w);
    u.h[4] = __float2bfloat16(b.x); u.h[5] = __float2bfloat16(b.y);
    u.h[6] = __float2bfloat16(b.z); u.h[7] = __float2bfloat16(b.w);
    return u.v;
}

__device__ __forceinline__ bf16x4 pack4(float4 a) {
    union { __hip_bfloat16 h[4]; bf16x4 v; } u;
    u.h[0] = __float2bfloat16(a.x); u.h[1] = __float2bfloat16(a.y);
    u.h[2] = __float2bfloat16(a.z); u.h[3] = __float2bfloat16(a.w);
    return u.v;
}

__global__ __launch_bounds__(256, 2)
void attn_kernel(const float* __restrict__ qg,
                 const float* __restrict__ kg,
                 const float* __restrict__ vg,
                 float* __restrict__ a_out,
                 float* __restrict__ o_out)
{
    // XCD-clustered decode: flat % 8 == b % 8, all 16 blocks of a batch
    // share an XCD for K/V L2 reuse.
    const int flat = blockIdx.x;
    const int xcd  = flat & 7;
    const int rdec = flat >> 3;          // 0..63
    const int jb   = rdec & 15;          // pair index 0..15
    const int b    = xcd + 8 * (rdec >> 4);

    const int tid  = threadIdx.x;
    const int wave = tid >> 6;
    const int lane = tid & 63;
    const int li   = lane & 15;
    const int quad = lane >> 4;

    __shared__ __hip_bfloat16 kl[64][Ddim + KPAD];  // K tile, row-major bf16
    __shared__ __hip_bfloat16 vt[Ddim][64 + PADV];  // V^T tile, XOR-swizzled cols
    __shared__ __hip_bfloat16 pt[64][64 + PADP];    // P (bf16), wave-private rows

    const size_t boff = (size_t)b * Sdim * Ddim;
    const float* qb = qg + boff;
    const float* kb = kg + boff;
    const float* vb = vg + boff;
    float* ab = a_out + (size_t)b * Sdim * Sdim;

    // per-thread staging geometry (same for loads and ds_writes)
    int skk[8], sd0[8];
    #pragma unroll
    for (int it = 0; it < 8; ++it) {
        const int idx = tid + it * 256;
        skk[it] = idx >> 5;              // key row 0..63
        sd0[it] = (idx & 31) * 4;        // dim col
    }

    for (int sel = 0; sel < 2; ++sel) {
        const int qi   = sel ? (NT - 1 - jb) : jb;
        const int q0   = qi * 64;
        const int row0 = q0 + wave * 16;

        // ---- Q fragments (A/B layout: [li][quad*8+j]), kept in regs ----
        bf16x8 qf[4];
        {
            const float* qrow = qb + (size_t)(row0 + li) * Ddim + quad * 8;
            #pragma unroll
            for (int ks = 0; ks < 4; ++ks)
                qf[ks] = pack8(qrow + ks * 32);
        }

        // ---- zero-fill fully-masked columns [64*(qi+1), S) ----
        {
            const int c0  = (qi + 1) * 64;
            const int zc4 = (Sdim - c0) >> 2;
            const f32x4 z = (f32x4){0.f, 0.f, 0.f, 0.f};
            for (int rr = 0; rr < 16; ++rr) {
                f32x4* dst = (f32x4*)(ab + (size_t)(row0 + rr) * Sdim + c0);
                for (int c = lane; c < zc4; c += 64)
                    __builtin_nontemporal_store(z, dst + c);
            }
        }

        // ========= Pass 1: swapped QK^T, per-lane m,l; no LDS, no barriers =========
        // S^T = mfma(A=K, B=Q): D[m=key-local][n=q-local]. Lane (li,quad):
        //   q-row = row0 + li (fixed), key-local = t*16 + quad*4 + r.
        float m_s = NEG_BIG, l_s = 0.f;

        for (int kt = 0; kt <= qi; ++kt) {
            const int kv0 = kt * 64;

            f32x4 acc[4];
            #pragma unroll
            for (int t = 0; t < 4; ++t) acc[t] = (f32x4){0.f, 0.f, 0.f, 0.f};

            #pragma unroll
            for (int t = 0; t < 4; ++t) {
                const float* kp = kb + (size_t)(kv0 + t * 16 + li) * Ddim + quad * 8;
                #pragma unroll
                for (int ks = 0; ks < 4; ++ks) {
                    bf16x8 kf = pack8(kp + ks * 32);
                    acc[t] = MFMA(kf, qf[ks], acc[t]);   // A=K, B=Q
                }
            }

            float s[4][4];
            float tm = NEG_BIG;
            #pragma unroll
            for (int t = 0; t < 4; ++t)
                #pragma unroll
                for (int r = 0; r < 4; ++r) {
                    float sv = acc[t][r] * INV_SCALE;
                    if (kt == qi) {
                        // key-local > q-local  => masked
                        if ((t * 16 + quad * 4 + r) > (wave * 16 + li)) sv = NEG_BIG;
                    }
                    s[t][r] = sv;
                    tm = fmaxf(tm, sv);
                }
            // reduce across the 4 quads holding the same q-row (li)
            tm = fmaxf(tm, __shfl_xor(tm, 16, 64));
            tm = fmaxf(tm, __shfl_xor(tm, 32, 64));

            float mn    = fmaxf(m_s, tm);
            float alpha = __expf(m_s - mn);   // 0 on first tile
            float se = 0.f;
            #pragma unroll
            for (int t = 0; t < 4; ++t)
                #pragma unroll
                for (int r = 0; r < 4; ++r)
                    se += __expf(s[t][r] - mn);
            se += __shfl_xor(se, 16, 64);
            se += __shfl_xor(se, 32, 64);
            l_s = l_s * alpha + se;
            m_s = mn;
        }

        // distribute per-row m, 1/l to the lanes that need them in pass 2
        const float invl_s = 1.0f / l_s;
        float m_r[4], invl_r[4];
        #pragma unroll
        for (int r = 0; r < 4; ++r) {
            m_r[r]    = __shfl(m_s,    quad * 4 + r, 64);
            invl_r[r] = __shfl(invl_s, quad * 4 + r, 64);
        }

        // =================== Pass 2: write a, accumulate O ===================
        f32x4 oacc[8];
        #pragma unroll
        for (int n = 0; n < 8; ++n) oacc[n] = (f32x4){0.f, 0.f, 0.f, 0.f};

        float4 kpre[8], vpre[8];
        #pragma unroll
        for (int it = 0; it < 8; ++it) {
            kpre[it] = *(const float4*)(kb + (size_t)skk[it] * Ddim + sd0[it]);
            vpre[it] = *(const float4*)(vb + (size_t)skk[it] * Ddim + sd0[it]);
        }

        for (int kt = 0; kt <= qi; ++kt) {
            const int kv0 = kt * 64;

            bar_lds();   // kl/vt/pt reads of previous tile complete block-wide
            #pragma unroll
            for (int it = 0; it < 8; ++it)
                *(bf16x4*)&kl[skk[it]][sd0[it]] = pack4(kpre[it]);
            #pragma unroll
            for (int it = 0; it < 8; ++it) {
                const int kk = skk[it], d0 = sd0[it];
                // XOR column-group swizzle; (d>>2) is constant over j (d0%4==0)
                const int cp = (((kk >> 3) ^ ((d0 >> 2) & 7)) << 3) | (kk & 7);
                float4 vv = vpre[it];
                vt[d0 + 0][cp] = __float2bfloat16(vv.x);
                vt[d0 + 1][cp] = __float2bfloat16(vv.y);
                vt[d0 + 2][cp] = __float2bfloat16(vv.z);
                vt[d0 + 3][cp] = __float2bfloat16(vv.w);
            }
            bar_lds();

            // prefetch next K,V tiles into regs (latency hides under compute)
            if (kt < qi) {
                const float* kbt = kb + (size_t)(kt + 1) * 64 * Ddim;
                const float* vbt = vb + (size_t)(kt + 1) * 64 * Ddim;
                #pragma unroll
                for (int it = 0; it < 8; ++it) {
                    kpre[it] = *(const float4*)(kbt + (size_t)skk[it] * Ddim + sd0[it]);
                    vpre[it] = *(const float4*)(vbt + (size_t)skk[it] * Ddim + sd0[it]);
                }
            }

            // S tile from LDS K (standard orientation: rows = q)
            f32x4 acc[4];
            #pragma unroll
            for (int t = 0; t < 4; ++t) acc[t] = (f32x4){0.f, 0.f, 0.f, 0.f};
            __builtin_amdgcn_s_setprio(1);
            #pragma unroll
            for (int t = 0; t < 4; ++t)
                #pragma unroll
                for (int ks = 0; ks < 4; ++ks) {
                    bf16x8 kf = *(const bf16x8*)&kl[t * 16 + li][ks * 32 + quad * 8];
                    acc[t] = MFMA(qf[ks], kf, acc[t]);
                }
            __builtin_amdgcn_s_setprio(0);

            // p = exp(s-m)/l -> pt (bf16, wave-private rows) + direct nt store to a
            #pragma unroll
            for (int r = 0; r < 4; ++r) {
                const int rowL = wave * 16 + quad * 4 + r;
                float* dst = ab + (size_t)(q0 + rowL) * Sdim + kv0 + li;
                #pragma unroll
                for (int t = 0; t < 4; ++t) {
                    float sv = acc[t][r] * INV_SCALE;
                    if (kt == qi && (kv0 + t * 16 + li) > (q0 + rowL)) sv = NEG_BIG;
                    float p = __expf(sv - m_r[r]) * invl_r[r];
                    pt[rowL][t * 16 + li] = __float2bfloat16(p);
                    __builtin_nontemporal_store(p, dst + t * 16);
                }
            }

            // in-wave cross-lane pt exchange: ds_writes landed before reads
            asm volatile("s_waitcnt lgkmcnt(0)" ::: "memory");

            // PV: O[16][128] += P[16][64] @ V[64][128]
            __builtin_amdgcn_s_setprio(1);
            #pragma unroll
            for (int ks = 0; ks < 2; ++ks) {
                bf16x8 pf = *(const bf16x8*)&pt[wave * 16 + li][ks * 32 + quad * 8];
                #pragma unroll
                for (int nt = 0; nt < 8; ++nt) {
                    const int row = nt * 16 + li;
                    const int g   = (row >> 2) & 7;
                    const int cb  = (((ks * 4 + quad) ^ g) << 3);
                    bf16x8 vf = *(const bf16x8*)&vt[row][cb];
                    oacc[nt] = MFMA(pf, vf, oacc[nt]);
                }
            }
            __builtin_amdgcn_s_setprio(0);
        }

        // ---- write O (fp32) ----
        float* ob = o_out + ((size_t)b * Sdim + row0) * Ddim;
        #pragma unroll
        for (int n = 0; n < 8; ++n)
            #pragma unroll
            for (int r = 0; r < 4; ++r)
                __builtin_nontemporal_store(oacc[n][r],
                    ob + (size_t)(quad * 4 + r) * Ddim + n * 16 + li);
    }
}

extern "C" void kernel_launch(void* const* d_in, const int* in_sizes, int n_in,
                              void* d_out, int out_size, void* d_ws, size_t ws_size,
                              hipStream_t stream)
{
    const float* q = (const float*)d_in[0];
    const float* k = (const float*)d_in[1];
    const float* v = (const float*)d_in[2];
    // d_in[3] = causal mask, ignored (reconstructed from indices)

    float* a = (float*)d_out;                             // [B,S,S]
    float* o = a + (size_t)BATCH * Sdim * Sdim;           // [B,S,D]

    attn_kernel<<<dim3(512), 256, 0, stream>>>(q, k, v, a, o);
}